// Round 9
// baseline (797.933 us; speedup 1.0000x reference)
//
#include <hip/hip_runtime.h>
#include <hip/hip_bf16.h>
#include <math.h>

#define H_ 100
#define W_ 152
#define HW_ 15200
#define C_ 512
#define A_ 9
#define NA_ 136800        // HW*A
#define PRE_NMS_ 6000
#define NB_PAD_ 6016      // PRE_NMS padded to 64
#define NWORDS_ 94        // ceil(6000/64)
#define POST_NMS_ 300

#define NCAND_ 16384      // candidate sort size (2^14)
#define NBUCK_ 262144     // 2^18 score buckets
#define SELW_  (NBUCK_ + 1024 + 16 + NCAND_ * 2)   // selection buffer words
#define SELN4_ (SELW_ / 4)                          // 73988 uint4

#define QH_ 102           // padded rows
#define QW_ 154           // padded cols
#define NQ_ (QH_ * QW_)   // 15708 padded positions

// pack_all block ranges
#define PX_BLOCKS_ 1968   // pack_x: 246 x 8
#define PW_BLOCKS_ 1152   // pack_w
#define PH_BLOCKS_ 128    // pack_head
#define ZC_BLOCKS_ 290    // zero selbuf (73988 uint4 / 256)
#define PALL_BLOCKS_ (PX_BLOCKS_ + PW_BLOCKS_ + PH_BLOCKS_ + ZC_BLOCKS_)

typedef __attribute__((ext_vector_type(8))) short short8;   // 8 bf16 (4 VGPRs)
typedef __attribute__((ext_vector_type(4))) float f32x4;    // MFMA C/D

#define GLOAD_LDS16(g, l) \
    __builtin_amdgcn_global_load_lds( \
        (const __attribute__((address_space(1))) void*)(g), \
        (__attribute__((address_space(3))) void*)(l), 16, 0, 0)

// ---------------------------------------------------------------------------
// pack_all: fused pack_x + pack_w + pack_head + zero(selbuf). One launch.
// ---------------------------------------------------------------------------
__global__ __launch_bounds__(256) void pack_all(
    const float* __restrict__ fm, const float* __restrict__ cw,
    const float* __restrict__ cls_w, const float* __restrict__ cls_b,
    const float* __restrict__ bbox_w, const float* __restrict__ bbox_b,
    __hip_bfloat16* __restrict__ xph, __hip_bfloat16* __restrict__ xpm,
    __hip_bfloat16* __restrict__ xpl,
    __hip_bfloat16* __restrict__ bph, __hip_bfloat16* __restrict__ bpm,
    __hip_bfloat16* __restrict__ bpl,
    float* __restrict__ wT, float* __restrict__ hb,
    unsigned* __restrict__ selbuf)
{
    __shared__ float t[64][65];
    const int tid = threadIdx.x;
    const int blk = blockIdx.x;

    if (blk < PX_BLOCKS_) {
        // ---- pack_x ----
        const int q0 = (blk % 246) * 64;
        const int c0 = (blk / 246) * 64;
        {
            const int qi = tid & 63;
            const int cs = tid >> 6;          // 0..3
            const int q = q0 + qi;
            int hp = q / QW_, wp = q - hp * QW_;
            bool inter = (q < NQ_) && (hp >= 1) && (hp <= 100) && (wp >= 1) && (wp <= 152);
            int p = inter ? ((hp - 1) * W_ + (wp - 1)) : 0;
#pragma unroll
            for (int cc = cs; cc < 64; cc += 4) {
                float v = inter ? fm[(size_t)(c0 + cc) * HW_ + p] : 0.f;
                t[cc][qi] = v;
            }
        }
        __syncthreads();
        {
            const int cl = tid & 63;
            const int qs = tid >> 6;
#pragma unroll
            for (int qq = qs; qq < 64; qq += 4) {
                int qg = q0 + qq;
                if (qg < NQ_) {
                    float v = t[cl][qq];
                    __hip_bfloat16 h = __float2bfloat16(v);
                    float r1 = v - __bfloat162float(h);
                    __hip_bfloat16 m = __float2bfloat16(r1);
                    float r2 = r1 - __bfloat162float(m);
                    __hip_bfloat16 l = __float2bfloat16(r2);
                    size_t o = (size_t)qg * 512 + c0 + cl;
                    xph[o] = h;
                    xpm[o] = m;
                    xpl[o] = l;
                }
            }
        }
        return;
    }
    if (blk < PX_BLOCKS_ + PW_BLOCKS_) {
        // ---- pack_w ----
        int id = (blk - PX_BLOCKS_) * 256 + tid;      // 294912 total
        int lane = id & 63;
        int rest = id >> 6;
        int n16 = rest & 31;
        int tk = rest >> 5;
        int k32 = tk & 15;
        int t9 = tk >> 4;
        if (t9 >= 9) return;
        int ky = t9 / 3, kx = t9 - ky * 3;
        int n = n16 * 16 + (lane & 15);
        int kb = k32 * 32 + (lane >> 4) * 8;

        union H8 { short8 s; __hip_bfloat16 b[8]; } hv, mv, lv;
#pragma unroll
        for (int j = 0; j < 8; j++) {
            int ci = kb + j;
            float v = cw[(((size_t)n * 512 + ci) * 3 + ky) * 3 + kx];
            __hip_bfloat16 h = __float2bfloat16(v);
            float r1 = v - __bfloat162float(h);
            __hip_bfloat16 m = __float2bfloat16(r1);
            float r2 = r1 - __bfloat162float(m);
            hv.b[j] = h;
            mv.b[j] = m;
            lv.b[j] = __float2bfloat16(r2);
        }
        *(short8*)((short*)bph + (size_t)id * 8) = hv.s;
        *(short8*)((short*)bpm + (size_t)id * 8) = mv.s;
        *(short8*)((short*)bpl + (size_t)id * 8) = lv.s;
        return;
    }
    if (blk < PX_BLOCKS_ + PW_BLOCKS_ + PH_BLOCKS_) {
        // ---- pack_head: wT[ci][c] + hb ----
        int id = (blk - PX_BLOCKS_ - PW_BLOCKS_) * 256 + tid;   // 32768
        int ci = id >> 6, c = id & 63;
        float v = 0.f;
        if (c < 18)      v = cls_w[(size_t)c * 512 + ci];
        else if (c < 54) v = bbox_w[(size_t)(c - 18) * 512 + ci];
        wT[ci * 64 + c] = v;
        if (ci == 0)
            hb[c] = (c < 18) ? cls_b[c] : (c < 54 ? bbox_b[c - 18] : 0.f);
        return;
    }
    {
        // ---- zero selbuf (cnt + segSum + meta + cand) ----
        int id = (blk - PX_BLOCKS_ - PW_BLOCKS_ - PH_BLOCKS_) * 256 + tid;
        if (id < SELN4_) ((uint4*)selbuf)[id] = make_uint4(0u, 0u, 0u, 0u);
    }
}

// ---------------------------------------------------------------------------
// conv_mfma: 3x3 conv as 9-tap implicit GEMM, bf16 3-term split, fp32 acc.
// v12: SPLIT-K diagnostic form (2 launches, its [0,72) and [72,144)).
// Bit-exact vs the fused version: half 2 resumes by loading half 1's raw
// fp32 partials as the MFMA C-input -- identical accumulation chain.
// Purpose: halve the per-dispatch duration (~341 -> ~175us) so rocprof's
// top-5 reveals any hidden kernel in the (175, 341)us range.
// ---------------------------------------------------------------------------
__global__ __launch_bounds__(256, 2) void conv_mfma(
    const __hip_bfloat16* __restrict__ xph, const __hip_bfloat16* __restrict__ xpm,
    const __hip_bfloat16* __restrict__ xpl,
    const __hip_bfloat16* __restrict__ bph, const __hip_bfloat16* __restrict__ bpm,
    const __hip_bfloat16* __restrict__ bpl,
    const float* __restrict__ cb, float* __restrict__ xt,
    int itBegin, int itEnd, int first, int last)
{
    __shared__ short a_lds[24][64][8];   // 24 KB, slot = mf*3 + arr
    __shared__ short b_lds[24][64][8];   // 24 KB, slot = nf*3 + arr

    const int tid = threadIdx.x;
    const int wave = tid >> 6, lane = tid & 63;
    const int wm = wave >> 1, wn = wave & 1;

    // --- XCD-aware bijective swizzle (m204): orig -> chunked wgid ---
    const int orig = blockIdx.x;          // 0..475, round-robins XCDs
    const int xcd  = orig & 7;
    const int idx  = orig >> 3;
    const int wgid = (xcd < 4 ? xcd * 60 : 240 + (xcd - 4) * 59) + idx;
    const int mb = wgid >> 2;             // 0..118
    const int nb = wgid & 3;              // 0..3 (fastest => same-mb co-XCD)

    const __hip_bfloat16* xarr[3] = {xph, xpm, xpl};
    const __hip_bfloat16* barr[3] = {bph, bpm, bpl};

    // staging: wave w owns slots w*6 .. w*6+5 (A and B)
    const int sBase = wave * 6;
    const short* aSrc[6];
    const short* bSrc[6];
#pragma unroll
    for (int i = 0; i < 6; i++) {
        int s = sBase + i;                // 0..23
        int f = s / 3, arr = s - 3 * (s / 3);
        int m = mb * 128 + f * 16 + (lane & 15);
        int hh = m / W_, ww = m - hh * W_;
        int q = (hh + 1) * QW_ + (ww + 1);
        aSrc[i] = (const short*)xarr[arr] + (size_t)q * 512 + (lane >> 4) * 8;
        bSrc[i] = (const short*)barr[arr] + (size_t)(nb * 8 + f) * 512 + lane * 8;
    }

    auto stage = [&](int it) {
        const int t9 = it >> 4;           // 144 = 9*16
        const int k32 = it & 15;
        const int t3 = t9 / 3;
        const int dy = t3 - 1, dx = t9 - t3 * 3 - 1;
        const int offA = ((dy * QW_ + dx) << 9) + (k32 << 5);  // shorts
        const int offB = it << 14;                              // shorts
#pragma unroll
        for (int i = 0; i < 6; i++) {
            GLOAD_LDS16(aSrc[i] + offA, &a_lds[sBase + i][0][0]);
            GLOAD_LDS16(bSrc[i] + offB, &b_lds[sBase + i][0][0]);
        }
    };

    const int col = lane & 15, quad = lane >> 4;

    f32x4 acc[4][4];
    if (first) {
#pragma unroll
        for (int f = 0; f < 4; f++)
#pragma unroll
            for (int g = 0; g < 4; g++)
                acc[f][g] = (f32x4){0.f, 0.f, 0.f, 0.f};
    } else {
        // resume: load raw partials (same (m,n) map as epilogue)
#pragma unroll
        for (int g = 0; g < 4; g++) {
            int n = nb * 128 + (wn * 4 + g) * 16 + col;
#pragma unroll
            for (int f = 0; f < 4; f++) {
                int m0 = mb * 128 + (wm * 4 + f) * 16 + quad * 4;
#pragma unroll
                for (int r = 0; r < 4; r++) {
                    int m = m0 + r;
                    acc[f][g][r] = (m < HW_) ? xt[(size_t)m * 512 + n] : 0.f;
                }
            }
        }
    }

    // prologue: first slab into LDS
    stage(itBegin);
    __syncthreads();

    for (int it = itBegin; it < itEnd; it++) {
        // (1) LDS -> regs: this wave's A and B fragments of slab(it)
        short8 ah[4], am[4], al[4], bh[4], bm[4], bl[4];
#pragma unroll
        for (int f = 0; f < 4; f++) {
            ah[f] = *(const short8*)&a_lds[(wm * 4 + f) * 3 + 0][lane][0];
            am[f] = *(const short8*)&a_lds[(wm * 4 + f) * 3 + 1][lane][0];
            al[f] = *(const short8*)&a_lds[(wm * 4 + f) * 3 + 2][lane][0];
            bh[f] = *(const short8*)&b_lds[(wn * 4 + f) * 3 + 0][lane][0];
            bm[f] = *(const short8*)&b_lds[(wn * 4 + f) * 3 + 1][lane][0];
            bl[f] = *(const short8*)&b_lds[(wn * 4 + f) * 3 + 2][lane][0];
        }
        // (2) all waves have their regs; LDS free for overwrite
        __syncthreads();
        // (3) issue next slab's loads early -- latency hides under MFMAs
        if (it + 1 < itEnd) stage(it + 1);
        // (4) compute from regs
#pragma unroll
        for (int g = 0; g < 4; g++) {
#pragma unroll
            for (int f = 0; f < 4; f++) {
                f32x4 a = acc[f][g];
                a = __builtin_amdgcn_mfma_f32_16x16x32_bf16(ah[f], bh[g], a, 0, 0, 0);
                a = __builtin_amdgcn_mfma_f32_16x16x32_bf16(ah[f], bm[g], a, 0, 0, 0);
                a = __builtin_amdgcn_mfma_f32_16x16x32_bf16(am[f], bh[g], a, 0, 0, 0);
                a = __builtin_amdgcn_mfma_f32_16x16x32_bf16(ah[f], bl[g], a, 0, 0, 0);
                a = __builtin_amdgcn_mfma_f32_16x16x32_bf16(al[f], bh[g], a, 0, 0, 0);
                a = __builtin_amdgcn_mfma_f32_16x16x32_bf16(am[f], bm[g], a, 0, 0, 0);
                acc[f][g] = a;
            }
        }
        // (5) staged slab(it+1) resident (vmcnt(0) drain inside barrier)
        __syncthreads();
    }

    // epilogue: raw partials (mid) or bias+relu (last)
#pragma unroll
    for (int g = 0; g < 4; g++) {
        int n = nb * 128 + (wn * 4 + g) * 16 + col;
        float bias = last ? cb[n] : 0.f;
#pragma unroll
        for (int f = 0; f < 4; f++) {
            int m0 = mb * 128 + (wm * 4 + f) * 16 + quad * 4;
#pragma unroll
            for (int r = 0; r < 4; r++) {
                int m = m0 + r;
                if (m < HW_) {
                    float v = acc[f][g][r];
                    xt[(size_t)m * 512 + n] = last ? fmaxf(v + bias, 0.f) : v;
                }
            }
        }
    }
}

// ---------------------------------------------------------------------------
// rpn_head: 1x1 convs + softmax fg + anchors + bbox transform + clip +
// min-size filter + fused 18-bit score histogram.
// ---------------------------------------------------------------------------
__device__ const float g_bx1[9] = {-84.f,-176.f,-360.f,-56.f,-120.f,-248.f,-36.f,-80.f,-168.f};
__device__ const float g_by1[9] = {-40.f,-88.f,-184.f,-56.f,-120.f,-248.f,-80.f,-168.f,-344.f};
__device__ const float g_bx2[9] = {99.f,191.f,375.f,71.f,135.f,263.f,51.f,95.f,183.f};
__device__ const float g_by2[9] = {55.f,103.f,199.f,71.f,135.f,263.f,95.f,183.f,359.f};

__global__ __launch_bounds__(256) void rpn_head(
    const float* __restrict__ xt,
    const float* __restrict__ wT, const float* __restrict__ hb,
    const float* __restrict__ im_info,
    float* __restrict__ scores, float4* __restrict__ boxes,
    unsigned* __restrict__ cnt)
{
    __shared__ float xl[16 * 512];
    __shared__ float raw[16][56];
    const int tid = threadIdx.x;
    const int p0 = blockIdx.x * 16;

    {
        const float4* src = (const float4*)(xt + (size_t)p0 * 512);
        float4* dst = (float4*)xl;
        for (int i = tid; i < 2048; i += 256) dst[i] = src[i];
    }
    __syncthreads();

    if (tid < 216) {
        int c  = tid % 54;
        int pg = tid / 54;
        float b = hb[c];
        float a0 = b, a1 = b, a2 = b, a3 = b;
        const float* x0 = xl + (size_t)(pg * 4) * 512;
        const float* wp = wT + c;
#pragma unroll 8
        for (int ci = 0; ci < 512; ci++) {
            float wv = wp[(size_t)ci * 64];   // wT[ci][c]: coalesced across lanes
            a0 = fmaf(wv, x0[ci], a0);
            a1 = fmaf(wv, x0[512 + ci], a1);
            a2 = fmaf(wv, x0[1024 + ci], a2);
            a3 = fmaf(wv, x0[1536 + ci], a3);
        }
        raw[pg * 4 + 0][c] = a0;
        raw[pg * 4 + 1][c] = a1;
        raw[pg * 4 + 2][c] = a2;
        raw[pg * 4 + 3][c] = a3;
    }
    __syncthreads();

    if (tid < 144) {
        int pos = tid / 9;
        int a   = tid % 9;
        int p = p0 + pos;
        int hh = p / 152;
        int ww = p - hh * 152;

        float s0 = raw[pos][a], s1 = raw[pos][9 + a];
        float fg = 1.f / (1.f + expf(s0 - s1));

        float dx = raw[pos][18 + 4 * a + 0];
        float dy = raw[pos][18 + 4 * a + 1];
        float dw = raw[pos][18 + 4 * a + 2];
        float dh = raw[pos][18 + 4 * a + 3];

        float sx = ww * 16.f, sy = hh * 16.f;
        float ax1 = g_bx1[a] + sx, ay1 = g_by1[a] + sy;
        float ax2 = g_bx2[a] + sx, ay2 = g_by2[a] + sy;
        float aw = ax2 - ax1 + 1.f, ah = ay2 - ay1 + 1.f;
        float axc = ax1 + 0.5f * aw, ayc = ay1 + 0.5f * ah;

        float px = dx * aw + axc, py = dy * ah + ayc;
        float pw = expf(dw) * aw, ph = expf(dh) * ah;
        float x1 = px - 0.5f * pw, y1 = py - 0.5f * ph;
        float x2 = px + 0.5f * pw, y2 = py + 0.5f * ph;

        float imh = im_info[0], imw = im_info[1], scl = im_info[2];
        x1 = fminf(fmaxf(x1, 0.f), imw - 1.f);
        y1 = fminf(fmaxf(y1, 0.f), imh - 1.f);
        x2 = fminf(fmaxf(x2, 0.f), imw - 1.f);
        y2 = fminf(fmaxf(y2, 0.f), imh - 1.f);

        float wd = x2 - x1 + 1.f, hd = y2 - y1 + 1.f;
        bool valid = (wd >= 16.f * scl) && (hd >= 16.f * scl);

        int idx = p * 9 + a;
        float sv = valid ? fg : -1000000000.f;
        scores[idx] = sv;
        boxes[idx] = make_float4(x1, y1, x2, y2);

        // fused histogram of sortable-score top-18 bits
        unsigned b32 = __float_as_uint(sv);
        unsigned u = (b32 & 0x80000000u) ? ~b32 : (b32 | 0x80000000u);
        atomicAdd(&cnt[u >> 14], 1u);
    }
}

// ---------------------------------------------------------------------------
// Exact top-K selection (proven parallel chain): seg_sum -> find_thresh
// -> compact -> 6-launch bitonic of 16384 -> gather.
// ---------------------------------------------------------------------------
__global__ __launch_bounds__(256) void seg_sum(const unsigned* __restrict__ cnt,
                                               unsigned* __restrict__ segSum)
{
    __shared__ unsigned sh[256];
    const int s = blockIdx.x;         // 0..1023
    const int t = threadIdx.x;
    sh[t] = cnt[s * 256 + t];
    __syncthreads();
    for (int o = 128; o > 0; o >>= 1) {
        if (t < o) sh[t] += sh[t + o];
        __syncthreads();
    }
    if (t == 0) segSum[s] = sh[0];
}

__global__ __launch_bounds__(256) void find_thresh(const unsigned* __restrict__ cnt,
                                                   const unsigned* __restrict__ segSum,
                                                   unsigned* __restrict__ meta)
{
    __shared__ unsigned sh[1024];
    __shared__ unsigned c2[256];
    __shared__ int sStarSh;
    __shared__ unsigned cumASh;
    const int t = threadIdx.x;
    for (int i = t; i < 1024; i += 256) sh[i] = segSum[i];
    __syncthreads();
    if (t == 0) {
        unsigned cum = 0; int sStar = 0; unsigned cumA = 0;
        for (int s = 1023; s >= 0; --s) {
            if (cum + sh[s] >= PRE_NMS_) { sStar = s; cumA = cum; break; }
            cum += sh[s];
        }
        sStarSh = sStar; cumASh = cumA;
    }
    __syncthreads();
    const int sStar = sStarSh;
    c2[t] = cnt[sStar * 256 + t];
    __syncthreads();
    if (t == 0) {
        unsigned cum2 = cumASh;
        int hh = 255;
        for (; hh >= 0; --hh) {
            cum2 += c2[hh];
            if (cum2 >= PRE_NMS_) break;
        }
        meta[0] = (unsigned)(sStar * 256 + hh);  // h* (bucket threshold)
        meta[1] = cum2;                          // |S| (diagnostic)
    }
}

__global__ __launch_bounds__(256) void compact_top(const float* __restrict__ scores,
                                                   const unsigned* __restrict__ meta,
                                                   unsigned long long* __restrict__ cand,
                                                   unsigned* __restrict__ ctr)
{
    int g = blockIdx.x * 256 + threadIdx.x;
    if (g >= NA_) return;
    unsigned hStar = meta[0];
    unsigned b = __float_as_uint(scores[g]);
    unsigned u = (b & 0x80000000u) ? ~b : (b | 0x80000000u);
    if ((u >> 14) >= hStar) {
        unsigned pos = atomicAdd(ctr, 1u);
        if (pos < (unsigned)NCAND_)
            cand[pos] = ((unsigned long long)u << 32) |
                        (unsigned long long)(0xFFFFFFFFu - (unsigned)g);
    }
}

__device__ __forceinline__ void cex(unsigned long long* s, int i, int l, bool desc)
{
    unsigned long long a = s[i], b = s[l];
    if (desc ? (a < b) : (a > b)) { s[i] = b; s[l] = a; }
}

__global__ __launch_bounds__(256) void bitonic_local_sort_keys(unsigned long long* __restrict__ keys)
{
    __shared__ unsigned long long s[4096];
    const int tid = threadIdx.x;
    const int base = blockIdx.x * 4096;
    for (int i = tid; i < 4096; i += 256) s[i] = keys[base + i];
    __syncthreads();
    for (int k = 2; k <= 4096; k <<= 1) {
        for (int j = k >> 1; j > 0; j >>= 1) {
#pragma unroll
            for (int m = 0; m < 8; m++) {
                int p = tid + m * 256;
                int i = ((p & ~(j - 1)) << 1) | (p & (j - 1));
                int l = i | j;
                bool desc = (((base + i) & k) == 0);
                cex(s, i, l, desc);
            }
            __syncthreads();
        }
    }
    for (int i = tid; i < 4096; i += 256) keys[base + i] = s[i];
}

__global__ void bitonic_global(unsigned long long* __restrict__ keys, int j, int k)
{
    int p = blockIdx.x * 256 + threadIdx.x;
    int i = ((p & ~(j - 1)) << 1) | (p & (j - 1));
    int l = i | j;
    bool desc = ((i & k) == 0);
    unsigned long long a = keys[i], b = keys[l];
    if (desc ? (a < b) : (a > b)) { keys[i] = b; keys[l] = a; }
}

__global__ __launch_bounds__(256) void bitonic_local_merge(unsigned long long* __restrict__ keys, int k)
{
    __shared__ unsigned long long s[4096];
    const int tid = threadIdx.x;
    const int base = blockIdx.x * 4096;
    const bool desc = ((base & k) == 0);
    for (int i = tid; i < 4096; i += 256) s[i] = keys[base + i];
    __syncthreads();
    for (int j = 2048; j > 0; j >>= 1) {
#pragma unroll
        for (int m = 0; m < 8; m++) {
            int p = tid + m * 256;
            int i = ((p & ~(j - 1)) << 1) | (p & (j - 1));
            cex(s, i, i | j, desc);
        }
        __syncthreads();
    }
    for (int i = tid; i < 4096; i += 256) keys[base + i] = s[i];
}

__global__ void gather_top(const unsigned long long* __restrict__ keys,
                           const float* __restrict__ scores,
                           const float4* __restrict__ boxes,
                           float4* __restrict__ nb, float* __restrict__ sc,
                           float* __restrict__ area)
{
    int r = blockIdx.x * 256 + threadIdx.x;
    if (r >= NB_PAD_) return;
    if (r < PRE_NMS_) {
        unsigned long long key = keys[r];
        unsigned idx = 0xFFFFFFFFu - (unsigned)(key & 0xFFFFFFFFull);
        float4 b = boxes[idx];
        nb[r] = b;
        sc[r] = scores[idx];
        area[r] = (b.z - b.x + 1.f) * (b.w - b.y + 1.f);
    } else {
        nb[r] = make_float4(0.f, 0.f, 0.f, 0.f);
        sc[r] = -1000000000.f;
        area[r] = 1.f;
    }
}

// ---------------------------------------------------------------------------
// NMS suppression bitmatrix, TRANSPOSED layout mask[word][box] so the hot
// store is wave-coalesced (512B/wave vs 64 scattered 8B lines). diag same.
// ---------------------------------------------------------------------------
__global__ __launch_bounds__(64) void nms_mask(const float4* __restrict__ nb,
                                               const float* __restrict__ area,
                                               unsigned long long* __restrict__ mask,
                                               unsigned long long* __restrict__ diag)
{
    __shared__ float4 cbox[64];
    __shared__ float carea[64];
    const int t = threadIdx.x;
    const int cbk = blockIdx.x, rb = blockIdx.y;
    const int jBase = cbk * 64;
    cbox[t] = nb[jBase + t];
    carea[t] = area[jBase + t];
    __syncthreads();

    const int i = rb * 64 + t;
    const float4 bi = nb[i];
    const float ai = area[i];
    unsigned long long bits = 0ull;
#pragma unroll 8
    for (int b = 0; b < 64; b++) {
        int j = jBase + b;
        if (j > i) {
            float4 bj = cbox[b];
            float xx1 = fmaxf(bi.x, bj.x), yy1 = fmaxf(bi.y, bj.y);
            float xx2 = fminf(bi.z, bj.z), yy2 = fminf(bi.w, bj.w);
            float iw = fmaxf(0.f, xx2 - xx1 + 1.f);
            float ih = fmaxf(0.f, yy2 - yy1 + 1.f);
            float inter = iw * ih;
            float iou = inter / (ai + carea[b] - inter);
            if (iou > 0.7f) bits |= (1ull << b);
        }
    }
    mask[(size_t)cbk * NB_PAD_ + i] = bits;   // transposed: coalesced store
    if (cbk == rb) diag[i] = bits;
}

// ---------------------------------------------------------------------------
// nms_final: block-serial NMS scan + final top-300 output, EXACT early exit.
// Reads the transposed mask: word w of row r at mask[w*NB_PAD_ + r].
// ---------------------------------------------------------------------------
__device__ __forceinline__ unsigned long long readlane_u64(unsigned long long v, int l)
{
    unsigned int lo = (unsigned int)__builtin_amdgcn_readlane((int)(unsigned int)(v & 0xffffffffull), l);
    unsigned int hi = (unsigned int)__builtin_amdgcn_readlane((int)(unsigned int)(v >> 32), l);
    return ((unsigned long long)hi << 32) | (unsigned long long)lo;
}

__global__ __launch_bounds__(256) void nms_final(const unsigned long long* __restrict__ mask,
                                                 const unsigned long long* __restrict__ diag,
                                                 const float* __restrict__ sc,
                                                 const float4* __restrict__ nb,
                                                 float* __restrict__ out)
{
    __shared__ unsigned long long dlds[NB_PAD_];
    __shared__ unsigned rlo[NWORDS_], rhi[NWORDS_];
    __shared__ unsigned long long aliveW[NWORDS_];
    __shared__ unsigned long long aliveSh;
    __shared__ int sel[POST_NMS_];
    __shared__ int brkSh, keptCumSh;
    const int tid = threadIdx.x;
    const int wave = tid >> 6, lane = tid & 63;

    for (int i = tid; i < NB_PAD_; i += 256) dlds[i] = diag[i];
    if (tid < NWORDS_) { rlo[tid] = 0u; rhi[tid] = 0u; }
    if (tid == 0) { brkSh = NWORDS_; keptCumSh = 0; }
    __syncthreads();

    for (int c = 0; c < NWORDS_; c++) {
        unsigned long long ext = ((unsigned long long)rhi[c] << 32) | (unsigned long long)rlo[c];
        unsigned long long aliveP = ~ext;

        unsigned long long mysel = aliveP & (0xFFFFull << (wave * 16));
        int rb[16];
        int n = 0;
        while (mysel) { rb[n++] = (int)__builtin_ctzll(mysel); mysel &= mysel - 1; }

        unsigned long long v0[16], v1[16];
#pragma unroll
        for (int i = 0; i < 16; i++) {
            if (i < n) {
                int row = c * 64 + rb[i];
                v0[i] = mask[(size_t)lane * NB_PAD_ + row];
                v1[i] = (lane < NWORDS_ - 64)
                          ? mask[(size_t)(64 + lane) * NB_PAD_ + row] : 0ull;
            }
        }

        if (wave == 0) {
            unsigned long long myD = dlds[c * 64 + lane];
            unsigned long long alive = aliveP, todo = aliveP;
            while (todo) {
                int l = (int)__builtin_ctzll(todo);
                todo &= todo - 1;
                unsigned long long d = readlane_u64(myD, l);
                alive &= ~d;
                todo &= ~d;
            }
            // count kept boxes that are also output-valid (sc > -5e8)
            bool vld = sc[c * 64 + lane] > -5e8f;
            unsigned long long vb = __ballot(vld);
            if (lane == 0) {
                aliveSh = alive;
                aliveW[c] = alive;
                keptCumSh += __popcll(alive & vb);
                if (keptCumSh >= POST_NMS_ && brkSh == NWORDS_) brkSh = c;
            }
        }
        __syncthreads();

        if (brkSh <= c) break;   // block-uniform: output determined

        unsigned long long alive = aliveSh;
        unsigned long long d0 = 0ull, d1 = 0ull;
#pragma unroll
        for (int i = 0; i < 16; i++) {
            if (i < n && ((alive >> rb[i]) & 1ull)) { d0 |= v0[i]; d1 |= v1[i]; }
        }
        if (d0) {
            atomicOr(&rlo[lane], (unsigned)d0);
            atomicOr(&rhi[lane], (unsigned)(d0 >> 32));
        }
        if (lane < NWORDS_ - 64 && d1) {
            atomicOr(&rlo[64 + lane], (unsigned)d1);
            atomicOr(&rhi[64 + lane], (unsigned)(d1 >> 32));
        }
        __syncthreads();
    }

    // ---- final top-300 selection (wave 0; columns 0..brkSh are final) ----
    if (wave == 0) {
        const unsigned long long lmask = (lane == 0) ? 0ull : ((~0ull) >> (64 - lane));
        int cntk = 0;
        for (int c = 0; c < NWORDS_ && cntk < POST_NMS_; c++) {
            int j = c * 64 + lane;
            bool k = (j < PRE_NMS_) && (((aliveW[c] >> lane) & 1ull) != 0ull) && (sc[j] > -5e8f);
            unsigned long long bal = __ballot(k);
            int pos = cntk + __popcll(bal & lmask);
            if (k && pos < POST_NMS_) sel[pos] = j;
            cntk += __popcll(bal);
        }
        if (cntk < POST_NMS_) {   // only reachable after a FULL scan
            for (int c = 0; c < NWORDS_ && cntk < POST_NMS_; c++) {
                int j = c * 64 + lane;
                bool k = (j < PRE_NMS_) && !((((aliveW[c] >> lane) & 1ull) != 0ull) && (sc[j] > -5e8f));
                unsigned long long bal = __ballot(k);
                int pos = cntk + __popcll(bal & lmask);
                if (k && pos < POST_NMS_) sel[pos] = j;
                cntk += __popcll(bal);
            }
        }
    }
    __syncthreads();
    for (int i = tid; i < POST_NMS_; i += 256) {
        int j = sel[i];
        float4 b = nb[j];
        out[i * 5 + 0] = 0.f;
        out[i * 5 + 1] = b.x;
        out[i * 5 + 2] = b.y;
        out[i * 5 + 3] = b.z;
        out[i * 5 + 4] = b.w;
    }
}

// ---------------------------------------------------------------------------
extern "C" void kernel_launch(void* const* d_in, const int* in_sizes, int n_in,
                              void* d_out, int out_size, void* d_ws, size_t ws_size,
                              hipStream_t stream)
{
    const float* fm      = (const float*)d_in[0];
    const float* im_info = (const float*)d_in[1];
    const float* conv_w  = (const float*)d_in[2];
    const float* conv_b  = (const float*)d_in[3];
    const float* cls_w   = (const float*)d_in[4];
    const float* cls_b   = (const float*)d_in[5];
    const float* bbox_w  = (const float*)d_in[6];
    const float* bbox_b  = (const float*)d_in[7];
    float* out = (float*)d_out;

    char* ws = (char*)d_ws;
    size_t off = 0;
    auto alloc = [&](size_t bytes) -> void* {
        void* p = ws + off;
        off = (off + bytes + 255) & ~(size_t)255;
        return p;
    };
    // persistent (non-aliased) across phases
    float* xt    = (float*)alloc((size_t)HW_ * 512 * 4);   // 31.1 MB
    float* wT    = (float*)alloc((size_t)512 * 64 * 4);    // 131 KB
    float* hb    = (float*)alloc(64 * 4);
    unsigned* selbuf = (unsigned*)alloc((size_t)SELW_ * 4); // 1.2 MB, zeroed in pack_all
    unsigned* cnt    = selbuf;
    unsigned* segSum = selbuf + NBUCK_;
    unsigned* meta   = selbuf + NBUCK_ + 1024;
    unsigned long long* cand = (unsigned long long*)(selbuf + NBUCK_ + 1024 + 16);

    // phase A (pre/during conv): bf16 split arrays.
    // phase B (post-conv): head outputs + NMS buffers. Aliased.
    size_t phase_base = off;
    __hip_bfloat16* xph = (__hip_bfloat16*)alloc((size_t)NQ_ * 512 * 2);     // 15.3 MiB
    __hip_bfloat16* xpm = (__hip_bfloat16*)alloc((size_t)NQ_ * 512 * 2);
    __hip_bfloat16* xpl = (__hip_bfloat16*)alloc((size_t)NQ_ * 512 * 2);
    __hip_bfloat16* bph = (__hip_bfloat16*)alloc((size_t)9 * 512 * 512 * 2); // 4.5 MiB
    __hip_bfloat16* bpm = (__hip_bfloat16*)alloc((size_t)9 * 512 * 512 * 2);
    __hip_bfloat16* bpl = (__hip_bfloat16*)alloc((size_t)9 * 512 * 512 * 2);

    off = phase_base;  // alias: phase-B buffers reuse phase-A memory
    float* scores             = (float*)alloc((size_t)NA_ * 4);
    float4* boxes             = (float4*)alloc((size_t)NA_ * 16);
    float4* nb                = (float4*)alloc((size_t)NB_PAD_ * 16);
    float* sc                 = (float*)alloc((size_t)NB_PAD_ * 4);
    float* area               = (float*)alloc((size_t)NB_PAD_ * 4);
    unsigned long long* mask  = (unsigned long long*)alloc((size_t)NB_PAD_ * NWORDS_ * 8);
    unsigned long long* diag  = (unsigned long long*)alloc((size_t)NB_PAD_ * 8);

    pack_all<<<dim3(PALL_BLOCKS_), 256, 0, stream>>>(
        fm, conv_w, cls_w, cls_b, bbox_w, bbox_b,
        xph, xpm, xpl, bph, bpm, bpl, wT, hb, selbuf);
    // split-K conv: bit-exact (half 2 resumes from half 1's raw partials)
    conv_mfma<<<dim3(476), 256, 0, stream>>>(xph, xpm, xpl, bph, bpm, bpl,
                                             conv_b, xt, 0, 72, 1, 0);
    conv_mfma<<<dim3(476), 256, 0, stream>>>(xph, xpm, xpl, bph, bpm, bpl,
                                             conv_b, xt, 72, 144, 0, 1);
    rpn_head<<<dim3(950), 256, 0, stream>>>(xt, wT, hb, im_info, scores, boxes, cnt);
    seg_sum<<<dim3(1024), 256, 0, stream>>>(cnt, segSum);
    find_thresh<<<dim3(1), 256, 0, stream>>>(cnt, segSum, meta);
    compact_top<<<dim3((NA_ + 255) / 256), 256, 0, stream>>>(scores, meta, cand,
                                                             meta + 2);
    bitonic_local_sort_keys<<<dim3(4), 256, 0, stream>>>(cand);
    bitonic_global<<<dim3(32), 256, 0, stream>>>(cand, 4096, 8192);
    bitonic_local_merge<<<dim3(4), 256, 0, stream>>>(cand, 8192);
    bitonic_global<<<dim3(32), 256, 0, stream>>>(cand, 8192, 16384);
    bitonic_global<<<dim3(32), 256, 0, stream>>>(cand, 4096, 16384);
    bitonic_local_merge<<<dim3(4), 256, 0, stream>>>(cand, 16384);
    gather_top<<<dim3((NB_PAD_ + 255) / 256), 256, 0, stream>>>(cand, scores, boxes,
                                                                nb, sc, area);
    nms_mask<<<dim3(NWORDS_, NWORDS_), 64, 0, stream>>>(nb, area, mask, diag);
    nms_final<<<dim3(1), 256, 0, stream>>>(mask, diag, sc, nb, out);
}

// Round 10
// 758.971 us; speedup vs baseline: 1.0513x; 1.0513x over previous
//
#include <hip/hip_runtime.h>
#include <hip/hip_bf16.h>
#include <math.h>

#define H_ 100
#define W_ 152
#define HW_ 15200
#define C_ 512
#define A_ 9
#define NA_ 136800        // HW*A
#define PRE_NMS_ 6000
#define NB_PAD_ 6016      // PRE_NMS padded to 64
#define NWORDS_ 94        // ceil(6000/64)
#define POST_NMS_ 300

#define NCAND_ 16384      // candidate sort size (2^14)
#define NBUCK_ 262144     // 2^18 score buckets
#define SELW_  (NBUCK_ + 1024 + 16 + NCAND_ * 2)   // selection buffer words
#define SELN4_ (SELW_ / 4)                          // 73988 uint4

#define QH_ 102           // padded rows
#define QW_ 154           // padded cols
#define NQ_ (QH_ * QW_)   // 15708 padded positions

// pack_all block ranges
#define PX_BLOCKS_ 1968   // pack_x: 246 x 8
#define PW_BLOCKS_ 1152   // pack_w
#define PH_BLOCKS_ 128    // pack_head
#define ZC_BLOCKS_ 290    // zero selbuf (73988 uint4 / 256)
#define PALL_BLOCKS_ (PX_BLOCKS_ + PW_BLOCKS_ + PH_BLOCKS_ + ZC_BLOCKS_)

typedef __attribute__((ext_vector_type(8))) short short8;   // 8 bf16 (4 VGPRs)
typedef __attribute__((ext_vector_type(4))) float f32x4;    // MFMA C/D

#define GLOAD_LDS16(g, l) \
    __builtin_amdgcn_global_load_lds( \
        (const __attribute__((address_space(1))) void*)(g), \
        (__attribute__((address_space(3))) void*)(l), 16, 0, 0)

// ---------------------------------------------------------------------------
// pack_all: fused pack_x + pack_w + pack_head + zero(selbuf). One launch.
// ---------------------------------------------------------------------------
__global__ __launch_bounds__(256) void pack_all(
    const float* __restrict__ fm, const float* __restrict__ cw,
    const float* __restrict__ cls_w, const float* __restrict__ cls_b,
    const float* __restrict__ bbox_w, const float* __restrict__ bbox_b,
    __hip_bfloat16* __restrict__ xph, __hip_bfloat16* __restrict__ xpm,
    __hip_bfloat16* __restrict__ xpl,
    __hip_bfloat16* __restrict__ bph, __hip_bfloat16* __restrict__ bpm,
    __hip_bfloat16* __restrict__ bpl,
    float* __restrict__ wT, float* __restrict__ hb,
    unsigned* __restrict__ selbuf)
{
    __shared__ float t[64][65];
    const int tid = threadIdx.x;
    const int blk = blockIdx.x;

    if (blk < PX_BLOCKS_) {
        // ---- pack_x ----
        const int q0 = (blk % 246) * 64;
        const int c0 = (blk / 246) * 64;
        {
            const int qi = tid & 63;
            const int cs = tid >> 6;          // 0..3
            const int q = q0 + qi;
            int hp = q / QW_, wp = q - hp * QW_;
            bool inter = (q < NQ_) && (hp >= 1) && (hp <= 100) && (wp >= 1) && (wp <= 152);
            int p = inter ? ((hp - 1) * W_ + (wp - 1)) : 0;
#pragma unroll
            for (int cc = cs; cc < 64; cc += 4) {
                float v = inter ? fm[(size_t)(c0 + cc) * HW_ + p] : 0.f;
                t[cc][qi] = v;
            }
        }
        __syncthreads();
        {
            const int cl = tid & 63;
            const int qs = tid >> 6;
#pragma unroll
            for (int qq = qs; qq < 64; qq += 4) {
                int qg = q0 + qq;
                if (qg < NQ_) {
                    float v = t[cl][qq];
                    __hip_bfloat16 h = __float2bfloat16(v);
                    float r1 = v - __bfloat162float(h);
                    __hip_bfloat16 m = __float2bfloat16(r1);
                    float r2 = r1 - __bfloat162float(m);
                    __hip_bfloat16 l = __float2bfloat16(r2);
                    size_t o = (size_t)qg * 512 + c0 + cl;
                    xph[o] = h;
                    xpm[o] = m;
                    xpl[o] = l;
                }
            }
        }
        return;
    }
    if (blk < PX_BLOCKS_ + PW_BLOCKS_) {
        // ---- pack_w ----
        int id = (blk - PX_BLOCKS_) * 256 + tid;      // 294912 total
        int lane = id & 63;
        int rest = id >> 6;
        int n16 = rest & 31;
        int tk = rest >> 5;
        int k32 = tk & 15;
        int t9 = tk >> 4;
        if (t9 >= 9) return;
        int ky = t9 / 3, kx = t9 - ky * 3;
        int n = n16 * 16 + (lane & 15);
        int kb = k32 * 32 + (lane >> 4) * 8;

        union H8 { short8 s; __hip_bfloat16 b[8]; } hv, mv, lv;
#pragma unroll
        for (int j = 0; j < 8; j++) {
            int ci = kb + j;
            float v = cw[(((size_t)n * 512 + ci) * 3 + ky) * 3 + kx];
            __hip_bfloat16 h = __float2bfloat16(v);
            float r1 = v - __bfloat162float(h);
            __hip_bfloat16 m = __float2bfloat16(r1);
            float r2 = r1 - __bfloat162float(m);
            hv.b[j] = h;
            mv.b[j] = m;
            lv.b[j] = __float2bfloat16(r2);
        }
        *(short8*)((short*)bph + (size_t)id * 8) = hv.s;
        *(short8*)((short*)bpm + (size_t)id * 8) = mv.s;
        *(short8*)((short*)bpl + (size_t)id * 8) = lv.s;
        return;
    }
    if (blk < PX_BLOCKS_ + PW_BLOCKS_ + PH_BLOCKS_) {
        // ---- pack_head: wT[ci][c] + hb ----
        int id = (blk - PX_BLOCKS_ - PW_BLOCKS_) * 256 + tid;   // 32768
        int ci = id >> 6, c = id & 63;
        float v = 0.f;
        if (c < 18)      v = cls_w[(size_t)c * 512 + ci];
        else if (c < 54) v = bbox_w[(size_t)(c - 18) * 512 + ci];
        wT[ci * 64 + c] = v;
        if (ci == 0)
            hb[c] = (c < 18) ? cls_b[c] : (c < 54 ? bbox_b[c - 18] : 0.f);
        return;
    }
    {
        // ---- zero selbuf (cnt + segSum + meta + cand) ----
        int id = (blk - PX_BLOCKS_ - PW_BLOCKS_ - PH_BLOCKS_) * 256 + tid;
        if (id < SELN4_) ((uint4*)selbuf)[id] = make_uint4(0u, 0u, 0u, 0u);
    }
}

// ---------------------------------------------------------------------------
// conv_mfma: 3x3 conv as 9-tap implicit GEMM, bf16 3-term split, fp32 acc.
// Fused form restored (v6-verbatim, verified 328-341us, MfmaUtil ~61%).
// v12's split-K diagnostic proved no hidden kernel >=190us exists.
// ---------------------------------------------------------------------------
__global__ __launch_bounds__(256, 2) void conv_mfma(
    const __hip_bfloat16* __restrict__ xph, const __hip_bfloat16* __restrict__ xpm,
    const __hip_bfloat16* __restrict__ xpl,
    const __hip_bfloat16* __restrict__ bph, const __hip_bfloat16* __restrict__ bpm,
    const __hip_bfloat16* __restrict__ bpl,
    const float* __restrict__ cb, float* __restrict__ xt)
{
    __shared__ short a_lds[24][64][8];   // 24 KB, slot = mf*3 + arr
    __shared__ short b_lds[24][64][8];   // 24 KB, slot = nf*3 + arr

    const int tid = threadIdx.x;
    const int wave = tid >> 6, lane = tid & 63;
    const int wm = wave >> 1, wn = wave & 1;

    // --- XCD-aware bijective swizzle (m204): orig -> chunked wgid ---
    const int orig = blockIdx.x;          // 0..475, round-robins XCDs
    const int xcd  = orig & 7;
    const int idx  = orig >> 3;
    const int wgid = (xcd < 4 ? xcd * 60 : 240 + (xcd - 4) * 59) + idx;
    const int mb = wgid >> 2;             // 0..118
    const int nb = wgid & 3;              // 0..3 (fastest => same-mb co-XCD)

    const __hip_bfloat16* xarr[3] = {xph, xpm, xpl};
    const __hip_bfloat16* barr[3] = {bph, bpm, bpl};

    // staging: wave w owns slots w*6 .. w*6+5 (A and B)
    const int sBase = wave * 6;
    const short* aSrc[6];
    const short* bSrc[6];
#pragma unroll
    for (int i = 0; i < 6; i++) {
        int s = sBase + i;                // 0..23
        int f = s / 3, arr = s - 3 * (s / 3);
        int m = mb * 128 + f * 16 + (lane & 15);
        int hh = m / W_, ww = m - hh * W_;
        int q = (hh + 1) * QW_ + (ww + 1);
        aSrc[i] = (const short*)xarr[arr] + (size_t)q * 512 + (lane >> 4) * 8;
        bSrc[i] = (const short*)barr[arr] + (size_t)(nb * 8 + f) * 512 + lane * 8;
    }

    auto stage = [&](int it) {
        const int t9 = it >> 4;           // 144 = 9*16
        const int k32 = it & 15;
        const int t3 = t9 / 3;
        const int dy = t3 - 1, dx = t9 - t3 * 3 - 1;
        const int offA = ((dy * QW_ + dx) << 9) + (k32 << 5);  // shorts
        const int offB = it << 14;                              // shorts
#pragma unroll
        for (int i = 0; i < 6; i++) {
            GLOAD_LDS16(aSrc[i] + offA, &a_lds[sBase + i][0][0]);
            GLOAD_LDS16(bSrc[i] + offB, &b_lds[sBase + i][0][0]);
        }
    };

    f32x4 acc[4][4];
#pragma unroll
    for (int f = 0; f < 4; f++)
#pragma unroll
        for (int g = 0; g < 4; g++)
            acc[f][g] = (f32x4){0.f, 0.f, 0.f, 0.f};

    // prologue: slab 0 into LDS
    stage(0);
    __syncthreads();

    for (int it = 0; it < 144; it++) {
        // (1) LDS -> regs: this wave's A and B fragments of slab(it)
        short8 ah[4], am[4], al[4], bh[4], bm[4], bl[4];
#pragma unroll
        for (int f = 0; f < 4; f++) {
            ah[f] = *(const short8*)&a_lds[(wm * 4 + f) * 3 + 0][lane][0];
            am[f] = *(const short8*)&a_lds[(wm * 4 + f) * 3 + 1][lane][0];
            al[f] = *(const short8*)&a_lds[(wm * 4 + f) * 3 + 2][lane][0];
            bh[f] = *(const short8*)&b_lds[(wn * 4 + f) * 3 + 0][lane][0];
            bm[f] = *(const short8*)&b_lds[(wn * 4 + f) * 3 + 1][lane][0];
            bl[f] = *(const short8*)&b_lds[(wn * 4 + f) * 3 + 2][lane][0];
        }
        // (2) all waves have their regs; LDS free for overwrite
        __syncthreads();
        // (3) issue next slab's loads early -- latency hides under MFMAs
        if (it + 1 < 144) stage(it + 1);
        // (4) compute from regs
#pragma unroll
        for (int g = 0; g < 4; g++) {
#pragma unroll
            for (int f = 0; f < 4; f++) {
                f32x4 a = acc[f][g];
                a = __builtin_amdgcn_mfma_f32_16x16x32_bf16(ah[f], bh[g], a, 0, 0, 0);
                a = __builtin_amdgcn_mfma_f32_16x16x32_bf16(ah[f], bm[g], a, 0, 0, 0);
                a = __builtin_amdgcn_mfma_f32_16x16x32_bf16(am[f], bh[g], a, 0, 0, 0);
                a = __builtin_amdgcn_mfma_f32_16x16x32_bf16(ah[f], bl[g], a, 0, 0, 0);
                a = __builtin_amdgcn_mfma_f32_16x16x32_bf16(al[f], bh[g], a, 0, 0, 0);
                a = __builtin_amdgcn_mfma_f32_16x16x32_bf16(am[f], bm[g], a, 0, 0, 0);
                acc[f][g] = a;
            }
        }
        // (5) staged slab(it+1) resident (vmcnt(0) drain inside barrier)
        __syncthreads();
    }

    // epilogue: C/D layout col=lane&15 (n), row=(lane>>4)*4+reg (m)
    const int col = lane & 15, quad = lane >> 4;
#pragma unroll
    for (int g = 0; g < 4; g++) {
        int n = nb * 128 + (wn * 4 + g) * 16 + col;
        float bias = cb[n];
#pragma unroll
        for (int f = 0; f < 4; f++) {
            int m0 = mb * 128 + (wm * 4 + f) * 16 + quad * 4;
#pragma unroll
            for (int r = 0; r < 4; r++) {
                int m = m0 + r;
                if (m < HW_)
                    xt[(size_t)m * 512 + n] = fmaxf(acc[f][g][r] + bias, 0.f);
            }
        }
    }
}

// ---------------------------------------------------------------------------
// rpn_head: 1x1 convs + softmax fg + anchors + bbox transform + clip +
// min-size filter + fused 18-bit score histogram.
// ---------------------------------------------------------------------------
__device__ const float g_bx1[9] = {-84.f,-176.f,-360.f,-56.f,-120.f,-248.f,-36.f,-80.f,-168.f};
__device__ const float g_by1[9] = {-40.f,-88.f,-184.f,-56.f,-120.f,-248.f,-80.f,-168.f,-344.f};
__device__ const float g_bx2[9] = {99.f,191.f,375.f,71.f,135.f,263.f,51.f,95.f,183.f};
__device__ const float g_by2[9] = {55.f,103.f,199.f,71.f,135.f,263.f,95.f,183.f,359.f};

__global__ __launch_bounds__(256) void rpn_head(
    const float* __restrict__ xt,
    const float* __restrict__ wT, const float* __restrict__ hb,
    const float* __restrict__ im_info,
    float* __restrict__ scores, float4* __restrict__ boxes,
    unsigned* __restrict__ cnt)
{
    __shared__ float xl[16 * 512];
    __shared__ float raw[16][56];
    const int tid = threadIdx.x;
    const int p0 = blockIdx.x * 16;

    {
        const float4* src = (const float4*)(xt + (size_t)p0 * 512);
        float4* dst = (float4*)xl;
        for (int i = tid; i < 2048; i += 256) dst[i] = src[i];
    }
    __syncthreads();

    if (tid < 216) {
        int c  = tid % 54;
        int pg = tid / 54;
        float b = hb[c];
        float a0 = b, a1 = b, a2 = b, a3 = b;
        const float* x0 = xl + (size_t)(pg * 4) * 512;
        const float* wp = wT + c;
#pragma unroll 8
        for (int ci = 0; ci < 512; ci++) {
            float wv = wp[(size_t)ci * 64];   // wT[ci][c]: coalesced across lanes
            a0 = fmaf(wv, x0[ci], a0);
            a1 = fmaf(wv, x0[512 + ci], a1);
            a2 = fmaf(wv, x0[1024 + ci], a2);
            a3 = fmaf(wv, x0[1536 + ci], a3);
        }
        raw[pg * 4 + 0][c] = a0;
        raw[pg * 4 + 1][c] = a1;
        raw[pg * 4 + 2][c] = a2;
        raw[pg * 4 + 3][c] = a3;
    }
    __syncthreads();

    if (tid < 144) {
        int pos = tid / 9;
        int a   = tid % 9;
        int p = p0 + pos;
        int hh = p / 152;
        int ww = p - hh * 152;

        float s0 = raw[pos][a], s1 = raw[pos][9 + a];
        float fg = 1.f / (1.f + expf(s0 - s1));

        float dx = raw[pos][18 + 4 * a + 0];
        float dy = raw[pos][18 + 4 * a + 1];
        float dw = raw[pos][18 + 4 * a + 2];
        float dh = raw[pos][18 + 4 * a + 3];

        float sx = ww * 16.f, sy = hh * 16.f;
        float ax1 = g_bx1[a] + sx, ay1 = g_by1[a] + sy;
        float ax2 = g_bx2[a] + sx, ay2 = g_by2[a] + sy;
        float aw = ax2 - ax1 + 1.f, ah = ay2 - ay1 + 1.f;
        float axc = ax1 + 0.5f * aw, ayc = ay1 + 0.5f * ah;

        float px = dx * aw + axc, py = dy * ah + ayc;
        float pw = expf(dw) * aw, ph = expf(dh) * ah;
        float x1 = px - 0.5f * pw, y1 = py - 0.5f * ph;
        float x2 = px + 0.5f * pw, y2 = py + 0.5f * ph;

        float imh = im_info[0], imw = im_info[1], scl = im_info[2];
        x1 = fminf(fmaxf(x1, 0.f), imw - 1.f);
        y1 = fminf(fmaxf(y1, 0.f), imh - 1.f);
        x2 = fminf(fmaxf(x2, 0.f), imw - 1.f);
        y2 = fminf(fmaxf(y2, 0.f), imh - 1.f);

        float wd = x2 - x1 + 1.f, hd = y2 - y1 + 1.f;
        bool valid = (wd >= 16.f * scl) && (hd >= 16.f * scl);

        int idx = p * 9 + a;
        float sv = valid ? fg : -1000000000.f;
        scores[idx] = sv;
        boxes[idx] = make_float4(x1, y1, x2, y2);

        // fused histogram of sortable-score top-18 bits
        unsigned b32 = __float_as_uint(sv);
        unsigned u = (b32 & 0x80000000u) ? ~b32 : (b32 | 0x80000000u);
        atomicAdd(&cnt[u >> 14], 1u);
    }
}

// ---------------------------------------------------------------------------
// Exact top-K selection: seg_sum -> find_thresh (PARALLEL suffix scans,
// replaces the 1280-iter serial LDS-latency loop ~70us -> ~5us) ->
// compact -> bitonic of 16384 (gather fused into last merge).
// ---------------------------------------------------------------------------
__global__ __launch_bounds__(256) void seg_sum(const unsigned* __restrict__ cnt,
                                               unsigned* __restrict__ segSum)
{
    __shared__ unsigned sh[256];
    const int s = blockIdx.x;         // 0..1023
    const int t = threadIdx.x;
    sh[t] = cnt[s * 256 + t];
    __syncthreads();
    for (int o = 128; o > 0; o >>= 1) {
        if (t < o) sh[t] += sh[t + o];
        __syncthreads();
    }
    if (t == 0) segSum[s] = sh[0];
}

// Parallel threshold finder. Semantics identical to the serial version:
// sStar = max{s : suffixIncl(s) >= PRE}, cumA = suffixExcl(sStar);
// hh = max{h : cumA + bucketSuffixIncl(h) >= PRE}; meta = {sStar*256+hh, cum2}.
// (Condition is monotone in s and h, so max-index == first crossing of the
// downward serial scan.)
__global__ __launch_bounds__(256) void find_thresh(const unsigned* __restrict__ cnt,
                                                   const unsigned* __restrict__ segSum,
                                                   unsigned* __restrict__ meta)
{
    __shared__ unsigned a[1024];
    __shared__ unsigned strip[256];
    __shared__ unsigned suf2[256];
    __shared__ int sStarSh, hStarSh;
    __shared__ unsigned cumASh;
    const int t = threadIdx.x;

    for (int i = t; i < 1024; i += 256) a[i] = segSum[i];
    if (t == 0) { sStarSh = -1; hStarSh = -1; }
    __syncthreads();

    const unsigned e0 = a[4 * t + 0], e1 = a[4 * t + 1];
    const unsigned e2 = a[4 * t + 2], e3 = a[4 * t + 3];
    const unsigned own = e0 + e1 + e2 + e3;
    strip[t] = own;
    __syncthreads();

    // suffix-inclusive scan over strips (Hillis-Steele)
    unsigned val = own;
    for (int o = 1; o < 256; o <<= 1) {
        unsigned w = (t + o < 256) ? strip[t + o] : 0u;
        __syncthreads();
        val += w;
        strip[t] = val;
        __syncthreads();
    }
    const unsigned sufExcl = strip[t] - own;   // sum of strips > t

    // per-segment suffix-inclusive within this strip
    unsigned si3 = sufExcl + e3;
    unsigned si2 = si3 + e2;
    unsigned si1 = si2 + e1;
    unsigned si0 = si1 + e0;
    int best = -1;
    if      (si3 >= PRE_NMS_) best = 4 * t + 3;
    else if (si2 >= PRE_NMS_) best = 4 * t + 2;
    else if (si1 >= PRE_NMS_) best = 4 * t + 1;
    else if (si0 >= PRE_NMS_) best = 4 * t + 0;
    if (best >= 0) atomicMax(&sStarSh, best);
    __syncthreads();
    const int sStar = sStarSh;
    if ((sStar >> 2) == t) {
        int r = sStar & 3;
        unsigned inc = (r == 3) ? si3 : (r == 2) ? si2 : (r == 1) ? si1 : si0;
        cumASh = inc - a[sStar];               // sum strictly above sStar
    }
    __syncthreads();
    const unsigned cumA = cumASh;

    // level 2: suffix-inclusive scan of the winning bucket row
    unsigned c = cnt[sStar * 256 + t];
    suf2[t] = c;
    __syncthreads();
    unsigned v2 = c;
    for (int o = 1; o < 256; o <<= 1) {
        unsigned w = (t + o < 256) ? suf2[t + o] : 0u;
        __syncthreads();
        v2 += w;
        suf2[t] = v2;
        __syncthreads();
    }
    if (cumA + suf2[t] >= PRE_NMS_) atomicMax(&hStarSh, t);
    __syncthreads();
    if (t == 0) {
        int hh = hStarSh;
        meta[0] = (unsigned)(sStar * 256 + hh);
        meta[1] = cumA + suf2[hh];
    }
}

__global__ __launch_bounds__(256) void compact_top(const float* __restrict__ scores,
                                                   const unsigned* __restrict__ meta,
                                                   unsigned long long* __restrict__ cand,
                                                   unsigned* __restrict__ ctr)
{
    int g = blockIdx.x * 256 + threadIdx.x;
    if (g >= NA_) return;
    unsigned hStar = meta[0];
    unsigned b = __float_as_uint(scores[g]);
    unsigned u = (b & 0x80000000u) ? ~b : (b | 0x80000000u);
    if ((u >> 14) >= hStar) {
        unsigned pos = atomicAdd(ctr, 1u);
        if (pos < (unsigned)NCAND_)
            cand[pos] = ((unsigned long long)u << 32) |
                        (unsigned long long)(0xFFFFFFFFu - (unsigned)g);
    }
}

__device__ __forceinline__ void cex(unsigned long long* s, int i, int l, bool desc)
{
    unsigned long long a = s[i], b = s[l];
    if (desc ? (a < b) : (a > b)) { s[i] = b; s[l] = a; }
}

__global__ __launch_bounds__(256) void bitonic_local_sort_keys(unsigned long long* __restrict__ keys)
{
    __shared__ unsigned long long s[4096];
    const int tid = threadIdx.x;
    const int base = blockIdx.x * 4096;
    for (int i = tid; i < 4096; i += 256) s[i] = keys[base + i];
    __syncthreads();
    for (int k = 2; k <= 4096; k <<= 1) {
        for (int j = k >> 1; j > 0; j >>= 1) {
#pragma unroll
            for (int m = 0; m < 8; m++) {
                int p = tid + m * 256;
                int i = ((p & ~(j - 1)) << 1) | (p & (j - 1));
                int l = i | j;
                bool desc = (((base + i) & k) == 0);
                cex(s, i, l, desc);
            }
            __syncthreads();
        }
    }
    for (int i = tid; i < 4096; i += 256) keys[base + i] = s[i];
}

__global__ void bitonic_global(unsigned long long* __restrict__ keys, int j, int k)
{
    int p = blockIdx.x * 256 + threadIdx.x;
    int i = ((p & ~(j - 1)) << 1) | (p & (j - 1));
    int l = i | j;
    bool desc = ((i & k) == 0);
    unsigned long long a = keys[i], b = keys[l];
    if (desc ? (a < b) : (a > b)) { keys[i] = b; keys[l] = a; }
}

__global__ __launch_bounds__(256) void bitonic_local_merge(unsigned long long* __restrict__ keys, int k)
{
    __shared__ unsigned long long s[4096];
    const int tid = threadIdx.x;
    const int base = blockIdx.x * 4096;
    const bool desc = ((base & k) == 0);
    for (int i = tid; i < 4096; i += 256) s[i] = keys[base + i];
    __syncthreads();
    for (int j = 2048; j > 0; j >>= 1) {
#pragma unroll
        for (int m = 0; m < 8; m++) {
            int p = tid + m * 256;
            int i = ((p & ~(j - 1)) << 1) | (p & (j - 1));
            cex(s, i, i | j, desc);
        }
        __syncthreads();
    }
    for (int i = tid; i < 4096; i += 256) keys[base + i] = s[i];
}

// Final merge (k = 16384) with the top-6016 gather fused: after the merge,
// rows [0, NB_PAD) live in blocks 0-1's LDS -- gather directly, saving a
// launch and a global key re-read.
__global__ __launch_bounds__(256) void bitonic_local_merge_gather(
    unsigned long long* __restrict__ keys, int k,
    const float* __restrict__ scores, const float4* __restrict__ boxes,
    float4* __restrict__ nb, float* __restrict__ sc, float* __restrict__ area)
{
    __shared__ unsigned long long s[4096];
    const int tid = threadIdx.x;
    const int base = blockIdx.x * 4096;
    const bool desc = ((base & k) == 0);
    for (int i = tid; i < 4096; i += 256) s[i] = keys[base + i];
    __syncthreads();
    for (int j = 2048; j > 0; j >>= 1) {
#pragma unroll
        for (int m = 0; m < 8; m++) {
            int p = tid + m * 256;
            int i = ((p & ~(j - 1)) << 1) | (p & (j - 1));
            cex(s, i, i | j, desc);
        }
        __syncthreads();
    }
    for (int i = tid; i < 4096; i += 256) {
        int r = base + i;
        keys[r] = s[i];
        if (r < NB_PAD_) {
            if (r < PRE_NMS_) {
                unsigned long long key = s[i];
                unsigned idx = 0xFFFFFFFFu - (unsigned)(key & 0xFFFFFFFFull);
                float4 b = boxes[idx];
                nb[r] = b;
                sc[r] = scores[idx];
                area[r] = (b.z - b.x + 1.f) * (b.w - b.y + 1.f);
            } else {
                nb[r] = make_float4(0.f, 0.f, 0.f, 0.f);
                sc[r] = -1000000000.f;
                area[r] = 1.f;
            }
        }
    }
}

// ---------------------------------------------------------------------------
// NMS suppression bitmatrix, transposed layout mask[word][box] (coalesced
// store). 256-thread blocks: 4 row-words share one cached column tile.
// ---------------------------------------------------------------------------
__global__ __launch_bounds__(256) void nms_mask(const float4* __restrict__ nb,
                                                const float* __restrict__ area,
                                                unsigned long long* __restrict__ mask,
                                                unsigned long long* __restrict__ diag)
{
    __shared__ float4 cbox[64];
    __shared__ float carea[64];
    const int t = threadIdx.x;
    const int cbk = blockIdx.x;
    const int rb  = blockIdx.y * 4 + (t >> 6);
    const int lane = t & 63;
    const int jBase = cbk * 64;
    if (t < 64) { cbox[t] = nb[jBase + t]; carea[t] = area[jBase + t]; }
    __syncthreads();
    if (rb >= NWORDS_) return;

    const int i = rb * 64 + lane;
    const float4 bi = nb[i];
    const float ai = area[i];
    unsigned long long bits = 0ull;
#pragma unroll 8
    for (int b = 0; b < 64; b++) {
        int j = jBase + b;
        if (j > i) {
            float4 bj = cbox[b];
            float xx1 = fmaxf(bi.x, bj.x), yy1 = fmaxf(bi.y, bj.y);
            float xx2 = fminf(bi.z, bj.z), yy2 = fminf(bi.w, bj.w);
            float iw = fmaxf(0.f, xx2 - xx1 + 1.f);
            float ih = fmaxf(0.f, yy2 - yy1 + 1.f);
            float inter = iw * ih;
            float iou = inter / (ai + carea[b] - inter);
            if (iou > 0.7f) bits |= (1ull << b);
        }
    }
    mask[(size_t)cbk * NB_PAD_ + i] = bits;   // transposed: coalesced store
    if (cbk == rb) diag[i] = bits;
}

// ---------------------------------------------------------------------------
// nms_final: block-serial NMS scan + final top-300 output, EXACT early exit.
// Reads the transposed mask: word w of row r at mask[w*NB_PAD_ + r].
// ---------------------------------------------------------------------------
__device__ __forceinline__ unsigned long long readlane_u64(unsigned long long v, int l)
{
    unsigned int lo = (unsigned int)__builtin_amdgcn_readlane((int)(unsigned int)(v & 0xffffffffull), l);
    unsigned int hi = (unsigned int)__builtin_amdgcn_readlane((int)(unsigned int)(v >> 32), l);
    return ((unsigned long long)hi << 32) | (unsigned long long)lo;
}

__global__ __launch_bounds__(256) void nms_final(const unsigned long long* __restrict__ mask,
                                                 const unsigned long long* __restrict__ diag,
                                                 const float* __restrict__ sc,
                                                 const float4* __restrict__ nb,
                                                 float* __restrict__ out)
{
    __shared__ unsigned long long dlds[NB_PAD_];
    __shared__ unsigned rlo[NWORDS_], rhi[NWORDS_];
    __shared__ unsigned long long aliveW[NWORDS_];
    __shared__ unsigned long long aliveSh;
    __shared__ int sel[POST_NMS_];
    __shared__ int brkSh, keptCumSh;
    const int tid = threadIdx.x;
    const int wave = tid >> 6, lane = tid & 63;

    for (int i = tid; i < NB_PAD_; i += 256) dlds[i] = diag[i];
    if (tid < NWORDS_) { rlo[tid] = 0u; rhi[tid] = 0u; }
    if (tid == 0) { brkSh = NWORDS_; keptCumSh = 0; }
    __syncthreads();

    for (int c = 0; c < NWORDS_; c++) {
        unsigned long long ext = ((unsigned long long)rhi[c] << 32) | (unsigned long long)rlo[c];
        unsigned long long aliveP = ~ext;

        unsigned long long mysel = aliveP & (0xFFFFull << (wave * 16));
        int rb[16];
        int n = 0;
        while (mysel) { rb[n++] = (int)__builtin_ctzll(mysel); mysel &= mysel - 1; }

        unsigned long long v0[16], v1[16];
#pragma unroll
        for (int i = 0; i < 16; i++) {
            if (i < n) {
                int row = c * 64 + rb[i];
                v0[i] = mask[(size_t)lane * NB_PAD_ + row];
                v1[i] = (lane < NWORDS_ - 64)
                          ? mask[(size_t)(64 + lane) * NB_PAD_ + row] : 0ull;
            }
        }

        if (wave == 0) {
            unsigned long long myD = dlds[c * 64 + lane];
            unsigned long long alive = aliveP, todo = aliveP;
            while (todo) {
                int l = (int)__builtin_ctzll(todo);
                todo &= todo - 1;
                unsigned long long d = readlane_u64(myD, l);
                alive &= ~d;
                todo &= ~d;
            }
            // count kept boxes that are also output-valid (sc > -5e8)
            bool vld = sc[c * 64 + lane] > -5e8f;
            unsigned long long vb = __ballot(vld);
            if (lane == 0) {
                aliveSh = alive;
                aliveW[c] = alive;
                keptCumSh += __popcll(alive & vb);
                if (keptCumSh >= POST_NMS_ && brkSh == NWORDS_) brkSh = c;
            }
        }
        __syncthreads();

        if (brkSh <= c) break;   // block-uniform: output determined

        unsigned long long alive = aliveSh;
        unsigned long long d0 = 0ull, d1 = 0ull;
#pragma unroll
        for (int i = 0; i < 16; i++) {
            if (i < n && ((alive >> rb[i]) & 1ull)) { d0 |= v0[i]; d1 |= v1[i]; }
        }
        if (d0) {
            atomicOr(&rlo[lane], (unsigned)d0);
            atomicOr(&rhi[lane], (unsigned)(d0 >> 32));
        }
        if (lane < NWORDS_ - 64 && d1) {
            atomicOr(&rlo[64 + lane], (unsigned)d1);
            atomicOr(&rhi[64 + lane], (unsigned)(d1 >> 32));
        }
        __syncthreads();
    }

    // ---- final top-300 selection (wave 0; columns 0..brkSh are final) ----
    if (wave == 0) {
        const unsigned long long lmask = (lane == 0) ? 0ull : ((~0ull) >> (64 - lane));
        int cntk = 0;
        for (int c = 0; c < NWORDS_ && cntk < POST_NMS_; c++) {
            int j = c * 64 + lane;
            bool k = (j < PRE_NMS_) && (((aliveW[c] >> lane) & 1ull) != 0ull) && (sc[j] > -5e8f);
            unsigned long long bal = __ballot(k);
            int pos = cntk + __popcll(bal & lmask);
            if (k && pos < POST_NMS_) sel[pos] = j;
            cntk += __popcll(bal);
        }
        if (cntk < POST_NMS_) {   // only reachable after a FULL scan
            for (int c = 0; c < NWORDS_ && cntk < POST_NMS_; c++) {
                int j = c * 64 + lane;
                bool k = (j < PRE_NMS_) && !((((aliveW[c] >> lane) & 1ull) != 0ull) && (sc[j] > -5e8f));
                unsigned long long bal = __ballot(k);
                int pos = cntk + __popcll(bal & lmask);
                if (k && pos < POST_NMS_) sel[pos] = j;
                cntk += __popcll(bal);
            }
        }
    }
    __syncthreads();
    for (int i = tid; i < POST_NMS_; i += 256) {
        int j = sel[i];
        float4 b = nb[j];
        out[i * 5 + 0] = 0.f;
        out[i * 5 + 1] = b.x;
        out[i * 5 + 2] = b.y;
        out[i * 5 + 3] = b.z;
        out[i * 5 + 4] = b.w;
    }
}

// ---------------------------------------------------------------------------
extern "C" void kernel_launch(void* const* d_in, const int* in_sizes, int n_in,
                              void* d_out, int out_size, void* d_ws, size_t ws_size,
                              hipStream_t stream)
{
    const float* fm      = (const float*)d_in[0];
    const float* im_info = (const float*)d_in[1];
    const float* conv_w  = (const float*)d_in[2];
    const float* conv_b  = (const float*)d_in[3];
    const float* cls_w   = (const float*)d_in[4];
    const float* cls_b   = (const float*)d_in[5];
    const float* bbox_w  = (const float*)d_in[6];
    const float* bbox_b  = (const float*)d_in[7];
    float* out = (float*)d_out;

    char* ws = (char*)d_ws;
    size_t off = 0;
    auto alloc = [&](size_t bytes) -> void* {
        void* p = ws + off;
        off = (off + bytes + 255) & ~(size_t)255;
        return p;
    };
    // persistent (non-aliased) across phases
    float* xt    = (float*)alloc((size_t)HW_ * 512 * 4);   // 31.1 MB
    float* wT    = (float*)alloc((size_t)512 * 64 * 4);    // 131 KB
    float* hb    = (float*)alloc(64 * 4);
    unsigned* selbuf = (unsigned*)alloc((size_t)SELW_ * 4); // 1.2 MB, zeroed in pack_all
    unsigned* cnt    = selbuf;
    unsigned* segSum = selbuf + NBUCK_;
    unsigned* meta   = selbuf + NBUCK_ + 1024;
    unsigned long long* cand = (unsigned long long*)(selbuf + NBUCK_ + 1024 + 16);

    // phase A (pre/during conv): bf16 split arrays.
    // phase B (post-conv): head outputs + NMS buffers. Aliased.
    size_t phase_base = off;
    __hip_bfloat16* xph = (__hip_bfloat16*)alloc((size_t)NQ_ * 512 * 2);     // 15.3 MiB
    __hip_bfloat16* xpm = (__hip_bfloat16*)alloc((size_t)NQ_ * 512 * 2);
    __hip_bfloat16* xpl = (__hip_bfloat16*)alloc((size_t)NQ_ * 512 * 2);
    __hip_bfloat16* bph = (__hip_bfloat16*)alloc((size_t)9 * 512 * 512 * 2); // 4.5 MiB
    __hip_bfloat16* bpm = (__hip_bfloat16*)alloc((size_t)9 * 512 * 512 * 2);
    __hip_bfloat16* bpl = (__hip_bfloat16*)alloc((size_t)9 * 512 * 512 * 2);

    off = phase_base;  // alias: phase-B buffers reuse phase-A memory
    float* scores             = (float*)alloc((size_t)NA_ * 4);
    float4* boxes             = (float4*)alloc((size_t)NA_ * 16);
    float4* nb                = (float4*)alloc((size_t)NB_PAD_ * 16);
    float* sc                 = (float*)alloc((size_t)NB_PAD_ * 4);
    float* area               = (float*)alloc((size_t)NB_PAD_ * 4);
    unsigned long long* mask  = (unsigned long long*)alloc((size_t)NB_PAD_ * NWORDS_ * 8);
    unsigned long long* diag  = (unsigned long long*)alloc((size_t)NB_PAD_ * 8);

    pack_all<<<dim3(PALL_BLOCKS_), 256, 0, stream>>>(
        fm, conv_w, cls_w, cls_b, bbox_w, bbox_b,
        xph, xpm, xpl, bph, bpm, bpl, wT, hb, selbuf);
    conv_mfma<<<dim3(476), 256, 0, stream>>>(xph, xpm, xpl, bph, bpm, bpl,
                                             conv_b, xt);
    rpn_head<<<dim3(950), 256, 0, stream>>>(xt, wT, hb, im_info, scores, boxes, cnt);
    seg_sum<<<dim3(1024), 256, 0, stream>>>(cnt, segSum);
    find_thresh<<<dim3(1), 256, 0, stream>>>(cnt, segSum, meta);
    compact_top<<<dim3((NA_ + 255) / 256), 256, 0, stream>>>(scores, meta, cand,
                                                             meta + 2);
    bitonic_local_sort_keys<<<dim3(4), 256, 0, stream>>>(cand);
    bitonic_global<<<dim3(32), 256, 0, stream>>>(cand, 4096, 8192);
    bitonic_local_merge<<<dim3(4), 256, 0, stream>>>(cand, 8192);
    bitonic_global<<<dim3(32), 256, 0, stream>>>(cand, 8192, 16384);
    bitonic_global<<<dim3(32), 256, 0, stream>>>(cand, 4096, 16384);
    bitonic_local_merge_gather<<<dim3(4), 256, 0, stream>>>(cand, 16384,
                                                            scores, boxes,
                                                            nb, sc, area);
    nms_mask<<<dim3(NWORDS_, 24), 256, 0, stream>>>(nb, area, mask, diag);
    nms_final<<<dim3(1), 256, 0, stream>>>(mask, diag, sc, nb, out);
}